// Round 1
// baseline (2757.893 us; speedup 1.0000x reference)
//
#include <hip/hip_runtime.h>
#include <hip/hip_bf16.h>
#include <math.h>

#define T_TOK 4096
#define H_DIM 2048
#define I_DIM 5632
#define N_EXP 8

typedef __attribute__((ext_vector_type(8))) short short8;
typedef __attribute__((ext_vector_type(4))) float floatx4;

__device__ __forceinline__ short f2bf(float f) {
  union { float f; unsigned u; } v; v.f = f;
  unsigned r = v.u + 0x7FFFu + ((v.u >> 16) & 1u);
  return (short)(r >> 16);
}
__device__ __forceinline__ float bf2f(short s) {
  union { unsigned u; float f; } v;
  v.u = ((unsigned)(unsigned short)s) << 16;
  return v.f;
}

// ---------------- small kernels ----------------

__global__ void zero_counts_kernel(int* counts) {
  if (threadIdx.x < N_EXP) counts[threadIdx.x] = 0;
}

__global__ void convx_kernel(const float* __restrict__ x, short* __restrict__ xbf) {
  int i = (blockIdx.x * 256 + threadIdx.x) * 4;  // total 8388608 elems, grid 8192
  float4 v = *(const float4*)(x + i);
  short4 o;
  o.x = f2bf(v.x); o.y = f2bf(v.y); o.z = f2bf(v.z); o.w = f2bf(v.w);
  *(short4*)(xbf + i) = o;
}

// one wave per token: logits = x[t] . rw[e], softmax, top-2
__global__ void router_kernel(const float* __restrict__ x, const float* __restrict__ rw,
                              int* __restrict__ topk_idx, float* __restrict__ topk_w,
                              int* __restrict__ counts) {
  int wave = threadIdx.x >> 6;
  int lane = threadIdx.x & 63;
  int t = blockIdx.x * 4 + wave;  // grid 1024 x 256 threads
  const float* xr = x + (size_t)t * H_DIM;
  float acc[N_EXP];
#pragma unroll
  for (int e = 0; e < N_EXP; ++e) acc[e] = 0.f;
  for (int h = lane; h < H_DIM; h += 64) {
    float xv = xr[h];
#pragma unroll
    for (int e = 0; e < N_EXP; ++e) acc[e] += xv * rw[e * H_DIM + h];
  }
#pragma unroll
  for (int off = 32; off > 0; off >>= 1) {
#pragma unroll
    for (int e = 0; e < N_EXP; ++e) acc[e] += __shfl_xor(acc[e], off);
  }
  if (lane == 0) {
    float m = acc[0];
#pragma unroll
    for (int e = 1; e < N_EXP; ++e) m = fmaxf(m, acc[e]);
    float p[N_EXP], s = 0.f;
#pragma unroll
    for (int e = 0; e < N_EXP; ++e) { p[e] = expf(acc[e] - m); s += p[e]; }
    float inv = 1.f / s;
#pragma unroll
    for (int e = 0; e < N_EXP; ++e) p[e] *= inv;
    int i1 = 0;
#pragma unroll
    for (int e = 1; e < N_EXP; ++e) if (p[e] > p[i1]) i1 = e;
    int i2 = (i1 == 0) ? 1 : 0;
#pragma unroll
    for (int e = 0; e < N_EXP; ++e) if (e != i1 && p[e] > p[i2]) i2 = e;
    topk_idx[2 * t] = i1; topk_idx[2 * t + 1] = i2;
    topk_w[2 * t] = p[i1]; topk_w[2 * t + 1] = p[i2];
    atomicAdd(&counts[i1], 1);
    atomicAdd(&counts[i2], 1);
  }
}

__global__ void offsets_kernel(const int* __restrict__ counts, int* __restrict__ offsets,
                               int* __restrict__ cursor) {
  if (threadIdx.x == 0) {
    int o = 0;
    for (int e = 0; e < N_EXP; ++e) { offsets[e] = o; o += counts[e]; }
    offsets[N_EXP] = o;
  }
  if (threadIdx.x < N_EXP) cursor[threadIdx.x] = 0;
}

__global__ void scatter_kernel(const int* __restrict__ topk_idx, const int* __restrict__ offsets,
                               int* __restrict__ cursor, int* __restrict__ tokmap,
                               int* __restrict__ rowpos) {
  int t = blockIdx.x * 256 + threadIdx.x;  // grid 16
  if (t >= T_TOK) return;
  for (int k = 0; k < 2; ++k) {
    int e = topk_idx[2 * t + k];
    int pos = atomicAdd(&cursor[e], 1);
    int row = offsets[e] + pos;
    tokmap[row] = t;
    rowpos[2 * t + k] = row;
  }
}

// ---------------- grouped GEMM: gate+up fused, SwiGLU epilogue ----------------
// grid: x = I_DIM/64 = 88, y = N_EXP*64 = 512 (64 worst-case M-blocks/expert)
__global__ __launch_bounds__(256) void gateup_kernel(
    const short* __restrict__ xbf, const float* __restrict__ wg,
    const float* __restrict__ wu, const int* __restrict__ counts,
    const int* __restrict__ offsets, const int* __restrict__ tokmap,
    short* __restrict__ hbuf) {
  const int e = blockIdx.y >> 6;
  const int mb = blockIdx.y & 63;
  const int cnt = counts[e];
  const int row0 = mb << 6;
  if (row0 >= cnt) return;
  const int off = offsets[e];
  const int n0 = blockIdx.x << 6;

  __shared__ __align__(16) short sA[64 * 40];
  __shared__ __align__(16) short sBg[64 * 40];
  __shared__ __align__(16) short sBu[64 * 40];
  __shared__ int stok[64];

  const int tid = threadIdx.x;
  if (tid < 64) {
    int r = row0 + tid;
    stok[tid] = (r < cnt) ? tokmap[off + r] : 0;
  }
  __syncthreads();

  const int sr = tid >> 2;          // staging row 0..63
  const int sc = (tid & 3) << 3;    // staging col 0,8,16,24
  const size_t wbase = (size_t)e * I_DIM * H_DIM + (size_t)(n0 + sr) * H_DIM + sc;
  const float* pg = wg + wbase;
  const float* pu = wu + wbase;
  const short* px = xbf + (size_t)stok[sr] * H_DIM + sc;
  const int woff = sr * 40 + sc;

  const int lane = tid & 63;
  const int wm = ((tid >> 6) & 1) << 5;  // wave m-offset 0/32
  const int wn = (tid >> 7) << 5;        // wave n-offset 0/32
  const int l15 = lane & 15;
  const int quad = lane >> 4;
  const int a0o = (wm + l15) * 40 + quad * 8;
  const int a1o = a0o + 16 * 40;
  const int b0o = (wn + l15) * 40 + quad * 8;
  const int b1o = b0o + 16 * 40;

  floatx4 accG[2][2] = {};
  floatx4 accU[2][2] = {};

  for (int k0 = 0; k0 < H_DIM; k0 += 32) {
    short8 xa = *(const short8*)(px + k0);
    float4 ga = *(const float4*)(pg + k0);
    float4 gb = *(const float4*)(pg + k0 + 4);
    float4 ua = *(const float4*)(pu + k0);
    float4 ub = *(const float4*)(pu + k0 + 4);
    short8 gvv, uvv;
    gvv[0] = f2bf(ga.x); gvv[1] = f2bf(ga.y); gvv[2] = f2bf(ga.z); gvv[3] = f2bf(ga.w);
    gvv[4] = f2bf(gb.x); gvv[5] = f2bf(gb.y); gvv[6] = f2bf(gb.z); gvv[7] = f2bf(gb.w);
    uvv[0] = f2bf(ua.x); uvv[1] = f2bf(ua.y); uvv[2] = f2bf(ua.z); uvv[3] = f2bf(ua.w);
    uvv[4] = f2bf(ub.x); uvv[5] = f2bf(ub.y); uvv[6] = f2bf(ub.z); uvv[7] = f2bf(ub.w);
    __syncthreads();
    *(short8*)&sA[woff] = xa;
    *(short8*)&sBg[woff] = gvv;
    *(short8*)&sBu[woff] = uvv;
    __syncthreads();
    short8 af0 = *(const short8*)&sA[a0o];
    short8 af1 = *(const short8*)&sA[a1o];
    short8 bg0 = *(const short8*)&sBg[b0o];
    short8 bg1 = *(const short8*)&sBg[b1o];
    short8 bu0 = *(const short8*)&sBu[b0o];
    short8 bu1 = *(const short8*)&sBu[b1o];
    accG[0][0] = __builtin_amdgcn_mfma_f32_16x16x32_bf16(af0, bg0, accG[0][0], 0, 0, 0);
    accG[0][1] = __builtin_amdgcn_mfma_f32_16x16x32_bf16(af0, bg1, accG[0][1], 0, 0, 0);
    accG[1][0] = __builtin_amdgcn_mfma_f32_16x16x32_bf16(af1, bg0, accG[1][0], 0, 0, 0);
    accG[1][1] = __builtin_amdgcn_mfma_f32_16x16x32_bf16(af1, bg1, accG[1][1], 0, 0, 0);
    accU[0][0] = __builtin_amdgcn_mfma_f32_16x16x32_bf16(af0, bu0, accU[0][0], 0, 0, 0);
    accU[0][1] = __builtin_amdgcn_mfma_f32_16x16x32_bf16(af0, bu1, accU[0][1], 0, 0, 0);
    accU[1][0] = __builtin_amdgcn_mfma_f32_16x16x32_bf16(af1, bu0, accU[1][0], 0, 0, 0);
    accU[1][1] = __builtin_amdgcn_mfma_f32_16x16x32_bf16(af1, bu1, accU[1][1], 0, 0, 0);
  }

#pragma unroll
  for (int f = 0; f < 2; ++f)
#pragma unroll
    for (int g = 0; g < 2; ++g)
#pragma unroll
      for (int i = 0; i < 4; ++i) {
        int rl = wm + f * 16 + quad * 4 + i;
        if (row0 + rl < cnt) {
          int col = n0 + wn + g * 16 + l15;
          float gv = accG[f][g][i];
          float uv = accU[f][g][i];
          float hv = gv / (1.f + __expf(-gv)) * uv;  // silu(g)*u
          hbuf[(size_t)(off + row0 + rl) * I_DIM + col] = f2bf(hv);
        }
      }
}

// ---------------- grouped GEMM: down projection ----------------
// grid: x = H_DIM/64 = 32, y = 512
__global__ __launch_bounds__(256) void down_kernel(
    const short* __restrict__ hbuf, const float* __restrict__ wd,
    const int* __restrict__ counts, const int* __restrict__ offsets,
    short* __restrict__ ybuf) {
  const int e = blockIdx.y >> 6;
  const int mb = blockIdx.y & 63;
  const int cnt = counts[e];
  const int row0 = mb << 6;
  if (row0 >= cnt) return;
  const int off = offsets[e];
  const int n0 = blockIdx.x << 6;

  __shared__ __align__(16) short sA[64 * 40];
  __shared__ __align__(16) short sB[64 * 40];

  const int tid = threadIdx.x;
  const int sr = tid >> 2;
  const int sc = (tid & 3) << 3;
  int arow = off + row0 + sr;
  if (arow > 2 * T_TOK - 1) arow = 2 * T_TOK - 1;  // clamp; masked at write
  const short* pa = hbuf + (size_t)arow * I_DIM + sc;
  const float* pb = wd + (size_t)e * H_DIM * I_DIM + (size_t)(n0 + sr) * I_DIM + sc;
  const int woff = sr * 40 + sc;

  const int lane = tid & 63;
  const int wm = ((tid >> 6) & 1) << 5;
  const int wn = (tid >> 7) << 5;
  const int l15 = lane & 15;
  const int quad = lane >> 4;
  const int a0o = (wm + l15) * 40 + quad * 8;
  const int a1o = a0o + 16 * 40;
  const int b0o = (wn + l15) * 40 + quad * 8;
  const int b1o = b0o + 16 * 40;

  floatx4 acc[2][2] = {};

  for (int k0 = 0; k0 < I_DIM; k0 += 32) {
    short8 av = *(const short8*)(pa + k0);
    float4 ba = *(const float4*)(pb + k0);
    float4 bb = *(const float4*)(pb + k0 + 4);
    short8 bv;
    bv[0] = f2bf(ba.x); bv[1] = f2bf(ba.y); bv[2] = f2bf(ba.z); bv[3] = f2bf(ba.w);
    bv[4] = f2bf(bb.x); bv[5] = f2bf(bb.y); bv[6] = f2bf(bb.z); bv[7] = f2bf(bb.w);
    __syncthreads();
    *(short8*)&sA[woff] = av;
    *(short8*)&sB[woff] = bv;
    __syncthreads();
    short8 af0 = *(const short8*)&sA[a0o];
    short8 af1 = *(const short8*)&sA[a1o];
    short8 bf0 = *(const short8*)&sB[b0o];
    short8 bf1 = *(const short8*)&sB[b1o];
    acc[0][0] = __builtin_amdgcn_mfma_f32_16x16x32_bf16(af0, bf0, acc[0][0], 0, 0, 0);
    acc[0][1] = __builtin_amdgcn_mfma_f32_16x16x32_bf16(af0, bf1, acc[0][1], 0, 0, 0);
    acc[1][0] = __builtin_amdgcn_mfma_f32_16x16x32_bf16(af1, bf0, acc[1][0], 0, 0, 0);
    acc[1][1] = __builtin_amdgcn_mfma_f32_16x16x32_bf16(af1, bf1, acc[1][1], 0, 0, 0);
  }

#pragma unroll
  for (int f = 0; f < 2; ++f)
#pragma unroll
    for (int g = 0; g < 2; ++g)
#pragma unroll
      for (int i = 0; i < 4; ++i) {
        int rl = wm + f * 16 + quad * 4 + i;
        if (row0 + rl < cnt) {
          int col = n0 + wn + g * 16 + l15;
          ybuf[(size_t)(off + row0 + rl) * H_DIM + col] = f2bf(acc[f][g][i]);
        }
      }
}

// out[t] = w0*y[p0] + w1*y[p1]; writes every element (no zeroing needed)
__global__ void combine_kernel(const short* __restrict__ ybuf, const int* __restrict__ rowpos,
                               const float* __restrict__ topk_w, float* __restrict__ out) {
  int v = blockIdx.x * 256 + threadIdx.x;  // grid 4096: 4096 tokens x 256 vec8
  int t = v >> 8;
  int c = (v & 255) << 3;
  int p0 = rowpos[2 * t], p1 = rowpos[2 * t + 1];
  float w0 = topk_w[2 * t], w1 = topk_w[2 * t + 1];
  short8 y0 = *(const short8*)(ybuf + (size_t)p0 * H_DIM + c);
  short8 y1 = *(const short8*)(ybuf + (size_t)p1 * H_DIM + c);
  float* po = out + (size_t)t * H_DIM + c;
  float4 o0, o1;
  o0.x = w0 * bf2f(y0[0]) + w1 * bf2f(y1[0]);
  o0.y = w0 * bf2f(y0[1]) + w1 * bf2f(y1[1]);
  o0.z = w0 * bf2f(y0[2]) + w1 * bf2f(y1[2]);
  o0.w = w0 * bf2f(y0[3]) + w1 * bf2f(y1[3]);
  o1.x = w0 * bf2f(y0[4]) + w1 * bf2f(y1[4]);
  o1.y = w0 * bf2f(y0[5]) + w1 * bf2f(y1[5]);
  o1.z = w0 * bf2f(y0[6]) + w1 * bf2f(y1[6]);
  o1.w = w0 * bf2f(y0[7]) + w1 * bf2f(y1[7]);
  *(float4*)po = o0;
  *(float4*)(po + 4) = o1;
}

// ---------------- launch ----------------

extern "C" void kernel_launch(void* const* d_in, const int* in_sizes, int n_in,
                              void* d_out, int out_size, void* d_ws, size_t ws_size,
                              hipStream_t stream) {
  const float* x  = (const float*)d_in[0];
  const float* rw = (const float*)d_in[1];
  const float* wg = (const float*)d_in[2];
  const float* wu = (const float*)d_in[3];
  const float* wd = (const float*)d_in[4];
  float* out = (float*)d_out;
  char* ws = (char*)d_ws;

  // workspace layout (~136 MiB)
  constexpr size_t XBF_OFF  = 0;                                  // 4096*2048*2
  constexpr size_t HBUF_OFF = XBF_OFF + (size_t)T_TOK * H_DIM * 2;        // 92,274,688
  constexpr size_t YBUF_OFF = HBUF_OFF + (size_t)2 * T_TOK * I_DIM * 2;   // 33,554,432
  constexpr size_t TIDX_OFF = YBUF_OFF + (size_t)2 * T_TOK * H_DIM * 2;
  constexpr size_t TW_OFF   = TIDX_OFF + (size_t)T_TOK * 2 * 4;
  constexpr size_t TOK_OFF  = TW_OFF + (size_t)T_TOK * 2 * 4;
  constexpr size_t RP_OFF   = TOK_OFF + (size_t)T_TOK * 2 * 4;
  constexpr size_t CNT_OFF  = RP_OFF + (size_t)T_TOK * 2 * 4;
  constexpr size_t OFFS_OFF = CNT_OFF + 256;
  constexpr size_t CUR_OFF  = OFFS_OFF + 256;

  short* xbf    = (short*)(ws + XBF_OFF);
  short* hbuf   = (short*)(ws + HBUF_OFF);
  short* ybuf   = (short*)(ws + YBUF_OFF);
  int* topk_idx = (int*)(ws + TIDX_OFF);
  float* topk_w = (float*)(ws + TW_OFF);
  int* tokmap   = (int*)(ws + TOK_OFF);
  int* rowpos   = (int*)(ws + RP_OFF);
  int* counts   = (int*)(ws + CNT_OFF);
  int* offsets  = (int*)(ws + OFFS_OFF);
  int* cursor   = (int*)(ws + CUR_OFF);

  zero_counts_kernel<<<1, 64, 0, stream>>>(counts);
  convx_kernel<<<(T_TOK * H_DIM) / (256 * 4), 256, 0, stream>>>(x, xbf);
  router_kernel<<<T_TOK / 4, 256, 0, stream>>>(x, rw, topk_idx, topk_w, counts);
  offsets_kernel<<<1, 64, 0, stream>>>(counts, offsets, cursor);
  scatter_kernel<<<T_TOK / 256, 256, 0, stream>>>(topk_idx, offsets, cursor, tokmap, rowpos);
  gateup_kernel<<<dim3(I_DIM / 64, N_EXP * 64), 256, 0, stream>>>(
      xbf, wg, wu, counts, offsets, tokmap, hbuf);
  down_kernel<<<dim3(H_DIM / 64, N_EXP * 64), 256, 0, stream>>>(
      hbuf, wd, counts, offsets, ybuf);
  combine_kernel<<<(T_TOK * H_DIM) / (256 * 8), 256, 0, stream>>>(ybuf, rowpos, topk_w, out);
}